// Round 1
// baseline (1832.611 us; speedup 1.0000x reference)
//
#include <hip/hip_runtime.h>

#define NN 100000
#define NE 1600000
#define DD 128
#define NL 5
#define NB 62
#define BN_EPS 1e-5f

static __device__ __forceinline__ float4 ld4(const float* p) { return *(const float4*)p; }

// ---------------- setup kernels ----------------

__global__ void k_init(int* deg_i, int* cnt, float* scale, float* shift, int n) {
    int i = blockIdx.x * 256 + threadIdx.x;
    if (i < n) { deg_i[i] = 1; cnt[i] = 1; }   // self-loop contributes 1 to both
    if (i < DD) { scale[i] = 1.f; shift[i] = 0.f; }
}

__global__ void k_count(const int* __restrict__ ei, int* deg_i, int* cnt) {
    int e = blockIdx.x * 256 + threadIdx.x;
    if (e < NE) {
        atomicAdd(&deg_i[ei[e]], 1);        // src occurrences -> deg
        atomicAdd(&cnt[ei[NE + e]], 1);     // dst occurrences -> CSR row sizes
    }
}

__global__ void k_dinv(const int* __restrict__ deg_i, float* __restrict__ dinv, int n) {
    int i = blockIdx.x * 256 + threadIdx.x;
    if (i < n) dinv[i] = rsqrtf((float)deg_i[i]);
}

// single-block exclusive scan of cnt[0..n) -> row_ptr, cursor; row_ptr[n] = total
__global__ void k_scan(const int* __restrict__ cnt, int* __restrict__ row_ptr,
                       int* __restrict__ cursor, int n) {
    __shared__ int tsum[1024];
    const int t = threadIdx.x;
    const int chunk = (n + 1023) / 1024;
    const int start = t * chunk;
    const int end = min(start + chunk, n);
    int s = 0;
    for (int i = start; i < end; ++i) s += cnt[i];
    tsum[t] = s;
    __syncthreads();
    for (int off = 1; off < 1024; off <<= 1) {
        int val = 0;
        if (t >= off) val = tsum[t - off];
        __syncthreads();
        if (t >= off) tsum[t] += val;
        __syncthreads();
    }
    int run = (t == 0) ? 0 : tsum[t - 1];
    for (int i = start; i < end; ++i) {
        row_ptr[i] = run; cursor[i] = run;
        run += cnt[i];
    }
    if (t == 1023) row_ptr[n] = run;
}

__global__ void k_scatter(const int* __restrict__ ei, const int* __restrict__ ea,
                          const float* __restrict__ dinv, int* cursor,
                          int* __restrict__ s_src, int* __restrict__ s_eid,
                          float* __restrict__ s_norm) {
    int idx = blockIdx.x * 256 + threadIdx.x;
    const int total = NE + NN;
    if (idx >= total) return;
    int s, d, eid;
    if (idx < NE) { s = ei[idx]; d = ei[NE + idx]; eid = ea[idx]; }
    else          { s = d = idx - NE; eid = 0; }
    int pos = atomicAdd(&cursor[d], 1);
    s_src[pos] = s; s_eid[pos] = eid;
    s_norm[pos] = dinv[s] * dinv[d];
}

__global__ void k_h0(const int* __restrict__ x, const float* __restrict__ emb,
                     float* __restrict__ X, int n) {
    int v = blockIdx.x * 8 + (threadIdx.x >> 5);
    if (v >= n) return;
    int c4 = (threadIdx.x & 31) * 4;
    *(float4*)&X[v * DD + c4] = ld4(&emb[x[v] * DD + c4]);
}

// ---------------- per-layer kernels ----------------

// C[m][nn] = sum_k f(A[m][k]) * W[nn][k] + bias[nn],  f = optional BN(scale,shift)+ReLU
__global__ __launch_bounds__(256) void k_gemm(const float* __restrict__ A,
                                              const float* __restrict__ W,
                                              const float* __restrict__ bias,
                                              const float* __restrict__ scale,
                                              const float* __restrict__ shift,
                                              float* __restrict__ C,
                                              int n, int relu) {
    __shared__ float As[64][132];   // As[k][m] (transposed)
    __shared__ float Bs[64][132];   // Bs[k][nn] = W[nn][k]
    const int tid = threadIdx.x;
    const int tx = tid & 15;
    const int ty = tid >> 4;
    const int r0 = blockIdx.x * 128;
    float acc[8][8];
#pragma unroll
    for (int i = 0; i < 8; ++i)
#pragma unroll
        for (int j = 0; j < 8; ++j) acc[i][j] = 0.f;

    for (int k0 = 0; k0 < DD; k0 += 64) {
        float4 sc = ld4(&scale[k0 + tx * 4]);
        float4 sh = ld4(&shift[k0 + tx * 4]);
#pragma unroll
        for (int i = 0; i < 8; ++i) {
            int m = ty + 16 * i;
            int row = r0 + m;
            float4 v = make_float4(0.f, 0.f, 0.f, 0.f);
            if (row < n) v = ld4(&A[row * DD + k0 + tx * 4]);
            v.x = fmaf(v.x, sc.x, sh.x); v.y = fmaf(v.y, sc.y, sh.y);
            v.z = fmaf(v.z, sc.z, sh.z); v.w = fmaf(v.w, sc.w, sh.w);
            if (relu) {
                v.x = fmaxf(v.x, 0.f); v.y = fmaxf(v.y, 0.f);
                v.z = fmaxf(v.z, 0.f); v.w = fmaxf(v.w, 0.f);
            }
            As[tx * 4 + 0][m] = v.x; As[tx * 4 + 1][m] = v.y;
            As[tx * 4 + 2][m] = v.z; As[tx * 4 + 3][m] = v.w;
        }
#pragma unroll
        for (int i = 0; i < 8; ++i) {
            int nn = ty + 16 * i;
            float4 v = ld4(&W[nn * DD + k0 + tx * 4]);
            Bs[tx * 4 + 0][nn] = v.x; Bs[tx * 4 + 1][nn] = v.y;
            Bs[tx * 4 + 2][nn] = v.z; Bs[tx * 4 + 3][nn] = v.w;
        }
        __syncthreads();
#pragma unroll 4
        for (int k = 0; k < 64; ++k) {
            float4 a0 = *(float4*)&As[k][ty * 8];
            float4 a1 = *(float4*)&As[k][ty * 8 + 4];
            float4 b0 = *(float4*)&Bs[k][tx * 8];
            float4 b1 = *(float4*)&Bs[k][tx * 8 + 4];
            float a[8] = {a0.x, a0.y, a0.z, a0.w, a1.x, a1.y, a1.z, a1.w};
            float b[8] = {b0.x, b0.y, b0.z, b0.w, b1.x, b1.y, b1.z, b1.w};
#pragma unroll
            for (int i = 0; i < 8; ++i)
#pragma unroll
                for (int j = 0; j < 8; ++j) acc[i][j] = fmaf(a[i], b[j], acc[i][j]);
        }
        __syncthreads();
    }
    float4 bi0 = ld4(&bias[tx * 8]);
    float4 bi1 = ld4(&bias[tx * 8 + 4]);
#pragma unroll
    for (int i = 0; i < 8; ++i) {
        int row = r0 + ty * 8 + i;
        if (row < n) {
            float4 o0 = make_float4(acc[i][0] + bi0.x, acc[i][1] + bi0.y,
                                    acc[i][2] + bi0.z, acc[i][3] + bi0.w);
            float4 o1 = make_float4(acc[i][4] + bi1.x, acc[i][5] + bi1.y,
                                    acc[i][6] + bi1.z, acc[i][7] + bi1.w);
            *(float4*)&C[row * DD + tx * 8] = o0;
            *(float4*)&C[row * DD + tx * 8 + 4] = o1;
        }
    }
}

// agg[v][:] = sum over incoming edges p: norm[p] * (hl[src[p]][:] + etab[eid[p]][:])
__global__ __launch_bounds__(256) void k_agg(const float* __restrict__ hl,
                                             const float* __restrict__ etab,
                                             const int* __restrict__ row_ptr,
                                             const int* __restrict__ s_src,
                                             const int* __restrict__ s_eid,
                                             const float* __restrict__ s_norm,
                                             float* __restrict__ agg, int n) {
    int v = blockIdx.x * 8 + (threadIdx.x >> 5);
    if (v >= n) return;
    int c4 = (threadIdx.x & 31) * 4;
    int p0 = row_ptr[v], p1 = row_ptr[v + 1];
    float4 acc = make_float4(0.f, 0.f, 0.f, 0.f);
    for (int p = p0; p < p1; ++p) {
        int s = s_src[p];
        int e = s_eid[p];
        float nr = s_norm[p];
        float4 hv = ld4(&hl[s * DD + c4]);
        float4 ev = ld4(&etab[e * DD + c4]);
        acc.x = fmaf(nr, hv.x + ev.x, acc.x);
        acc.y = fmaf(nr, hv.y + ev.y, acc.y);
        acc.z = fmaf(nr, hv.z + ev.z, acc.z);
        acc.w = fmaf(nr, hv.w + ev.w, acc.w);
    }
    *(float4*)&agg[v * DD + c4] = acc;
}

__global__ __launch_bounds__(256) void k_bnstats(const float* __restrict__ X,
                                                 float* __restrict__ psumA,
                                                 float* __restrict__ psumB, int n) {
    __shared__ float ls[DD], lss[DD];
    int tid = threadIdx.x;
    if (tid < DD) { ls[tid] = 0.f; lss[tid] = 0.f; }
    __syncthreads();
    int half = tid >> 5;
    int c4 = (tid & 31) * 4;
    float4 s = make_float4(0.f, 0.f, 0.f, 0.f);
    float4 ss = make_float4(0.f, 0.f, 0.f, 0.f);
    for (int v = blockIdx.x * 8 + half; v < n; v += gridDim.x * 8) {
        float4 x = ld4(&X[v * DD + c4]);
        s.x += x.x; s.y += x.y; s.z += x.z; s.w += x.w;
        ss.x = fmaf(x.x, x.x, ss.x); ss.y = fmaf(x.y, x.y, ss.y);
        ss.z = fmaf(x.z, x.z, ss.z); ss.w = fmaf(x.w, x.w, ss.w);
    }
    atomicAdd(&ls[c4 + 0], s.x); atomicAdd(&ls[c4 + 1], s.y);
    atomicAdd(&ls[c4 + 2], s.z); atomicAdd(&ls[c4 + 3], s.w);
    atomicAdd(&lss[c4 + 0], ss.x); atomicAdd(&lss[c4 + 1], ss.y);
    atomicAdd(&lss[c4 + 2], ss.z); atomicAdd(&lss[c4 + 3], ss.w);
    __syncthreads();
    if (tid < DD) {
        psumA[blockIdx.x * DD + tid] = ls[tid];
        psumB[blockIdx.x * DD + tid] = lss[tid];
    }
}

__global__ void k_bnfinal(const float* __restrict__ psumA, const float* __restrict__ psumB,
                          const float* __restrict__ gamma, const float* __restrict__ beta,
                          float* __restrict__ scale, float* __restrict__ shift,
                          int n, int nblk) {
    int d = threadIdx.x;   // 128 threads
    float s = 0.f, ss = 0.f;
    for (int b = 0; b < nblk; ++b) { s += psumA[b * DD + d]; ss += psumB[b * DD + d]; }
    float mean = s / (float)n;
    float var = ss / (float)n - mean * mean;
    float sc = gamma[d] * rsqrtf(var + BN_EPS);
    scale[d] = sc;
    shift[d] = beta[d] - mean * sc;
}

__global__ void k_bnapply(float* __restrict__ X, const float* __restrict__ scale,
                          const float* __restrict__ shift, int total4) {
    int i = blockIdx.x * blockDim.x + threadIdx.x;
    int stride = gridDim.x * blockDim.x;
    for (; i < total4; i += stride) {
        int c = (i & 31) << 2;
        float4 v = *(float4*)&X[i * 4];
        float4 sc = ld4(&scale[c]);
        float4 sh = ld4(&shift[c]);
        v.x = fmaf(v.x, sc.x, sh.x); v.y = fmaf(v.y, sc.y, sh.y);
        v.z = fmaf(v.z, sc.z, sh.z); v.w = fmaf(v.w, sc.w, sh.w);
        *(float4*)&X[i * 4] = v;
    }
}

// ---------------- launch ----------------

extern "C" void kernel_launch(void* const* d_in, const int* in_sizes, int n_in,
                              void* d_out, int out_size, void* d_ws, size_t ws_size,
                              hipStream_t stream) {
    const int* x        = (const int*)d_in[0];
    const int* ei       = (const int*)d_in[1];
    const int* ea       = (const int*)d_in[2];
    const float* x_emb  = (const float*)d_in[3];
    const float* lin_w  = (const float*)d_in[4];
    const float* lin_b  = (const float*)d_in[5];
    const float* etab   = (const float*)d_in[6];
    const float* gamma  = (const float*)d_in[7];
    const float* beta   = (const float*)d_in[8];
    float* X = (float*)d_out;

    char* w = (char*)d_ws;
    size_t off = 0;
    auto alloc = [&](size_t bytes) -> void* {
        off = (off + 255) & ~(size_t)255;
        void* p = w + off;
        off += bytes;
        return p;
    };
    float* hl     = (float*)alloc((size_t)NN * DD * 4);
    int*   s_src  = (int*)alloc((size_t)(NE + NN) * 4);
    int*   s_eid  = (int*)alloc((size_t)(NE + NN) * 4);
    float* s_norm = (float*)alloc((size_t)(NE + NN) * 4);
    int*   deg_i  = (int*)alloc((size_t)NN * 4);
    int*   cnt    = (int*)alloc((size_t)NN * 4);
    int*   rowp   = (int*)alloc((size_t)(NN + 1) * 4);
    int*   cursor = (int*)alloc((size_t)NN * 4);
    float* dinv   = (float*)alloc((size_t)NN * 4);
    float* psumA  = (float*)alloc((size_t)256 * DD * 4);
    float* psumB  = (float*)alloc((size_t)256 * DD * 4);
    float* scale  = (float*)alloc((size_t)DD * 4);
    float* shift  = (float*)alloc((size_t)DD * 4);

    k_init<<<(NN + 255) / 256, 256, 0, stream>>>(deg_i, cnt, scale, shift, NN);
    k_count<<<(NE + 255) / 256, 256, 0, stream>>>(ei, deg_i, cnt);
    k_dinv<<<(NN + 255) / 256, 256, 0, stream>>>(deg_i, dinv, NN);
    k_scan<<<1, 1024, 0, stream>>>(cnt, rowp, cursor, NN);
    k_scatter<<<(NE + NN + 255) / 256, 256, 0, stream>>>(ei, ea, dinv, cursor,
                                                         s_src, s_eid, s_norm);
    k_h0<<<(NN + 7) / 8, 256, 0, stream>>>(x, x_emb, X, NN);

    for (int l = 0; l < NL; ++l) {
        k_gemm<<<(NN + 127) / 128, 256, 0, stream>>>(X, lin_w + (size_t)l * DD * DD,
                                                     lin_b + (size_t)l * DD,
                                                     scale, shift, hl, NN, l > 0 ? 1 : 0);
        k_agg<<<(NN + 7) / 8, 256, 0, stream>>>(hl, etab + (size_t)l * NB * DD,
                                                rowp, s_src, s_eid, s_norm, X, NN);
        k_bnstats<<<256, 256, 0, stream>>>(X, psumA, psumB, NN);
        k_bnfinal<<<1, DD, 0, stream>>>(psumA, psumB, gamma + (size_t)l * DD,
                                        beta + (size_t)l * DD, scale, shift, NN, 256);
    }
    k_bnapply<<<(NN * DD / 4 + 255) / 256, 256, 0, stream>>>(X, scale, shift, NN * DD / 4);
}

// Round 2
// 1618.067 us; speedup vs baseline: 1.1326x; 1.1326x over previous
//
#include <hip/hip_runtime.h>

#define NN 100000
#define NE 1600000
#define DD 128
#define NL 5
#define NB 62
#define BN_EPS 1e-5f

static __device__ __forceinline__ float4 ld4(const float* p) { return *(const float4*)p; }

// ---------------- setup kernels ----------------

__global__ void k_init(int* deg_i, int* cnt, float* scale, float* shift,
                       int* row_ptr, int n) {
    int i = blockIdx.x * 256 + threadIdx.x;
    if (i < n) { deg_i[i] = 1; cnt[i] = 1; }   // self-loop contributes 1 to both
    if (i < DD) { scale[i] = 1.f; shift[i] = 0.f; }
    if (i == 0) row_ptr[NN] = NE + NN;         // total is static
}

__global__ void k_count(const int* __restrict__ ei, int* deg_i, int* cnt) {
    int e = blockIdx.x * 256 + threadIdx.x;
    if (e < NE) {
        atomicAdd(&deg_i[ei[e]], 1);        // src occurrences -> deg
        atomicAdd(&cnt[ei[NE + e]], 1);     // dst occurrences -> CSR row sizes
    }
}

__global__ void k_dinv(const int* __restrict__ deg_i, float* __restrict__ dinv, int n) {
    int i = blockIdx.x * 256 + threadIdx.x;
    if (i < n) dinv[i] = rsqrtf((float)deg_i[i]);
}

// ---- 3-phase device-wide exclusive scan of cnt[0..NN) -> row_ptr, cursor ----

// phase 1: per-block (256-wide) sums
__global__ void k_scan_bsum(const int* __restrict__ cnt, int* __restrict__ bsum, int n) {
    __shared__ int s[256];
    int i = blockIdx.x * 256 + threadIdx.x;
    int v = (i < n) ? cnt[i] : 0;
    s[threadIdx.x] = v;
    __syncthreads();
    for (int off = 128; off > 0; off >>= 1) {
        if (threadIdx.x < off) s[threadIdx.x] += s[threadIdx.x + off];
        __syncthreads();
    }
    if (threadIdx.x == 0) bsum[blockIdx.x] = s[0];
}

// phase 2: single-block scan of block sums (nblk <= 1024) -> exclusive boffs
__global__ void k_scan_boffs(const int* __restrict__ bsum, int* __restrict__ boffs,
                             int nblk) {
    __shared__ int s[1024];
    int t = threadIdx.x;
    int v = (t < nblk) ? bsum[t] : 0;
    s[t] = v;
    __syncthreads();
    for (int off = 1; off < 1024; off <<= 1) {
        int val = (t >= off) ? s[t - off] : 0;
        __syncthreads();
        s[t] += val;
        __syncthreads();
    }
    if (t < nblk) boffs[t] = s[t] - v;   // exclusive
}

// phase 3: per-block exclusive scan + block offset -> row_ptr, cursor
__global__ void k_scan_apply(const int* __restrict__ cnt, const int* __restrict__ boffs,
                             int* __restrict__ row_ptr, int* __restrict__ cursor, int n) {
    __shared__ int s[256];
    int i = blockIdx.x * 256 + threadIdx.x;
    int t = threadIdx.x;
    int v = (i < n) ? cnt[i] : 0;
    s[t] = v;
    __syncthreads();
    for (int off = 1; off < 256; off <<= 1) {
        int val = (t >= off) ? s[t - off] : 0;
        __syncthreads();
        s[t] += val;
        __syncthreads();
    }
    if (i < n) {
        int excl = s[t] - v + boffs[blockIdx.x];
        row_ptr[i] = excl;
        cursor[i] = excl;
    }
}

__global__ void k_scatter(const int* __restrict__ ei, const int* __restrict__ ea,
                          const float* __restrict__ dinv, int* cursor,
                          int* __restrict__ s_src, int* __restrict__ s_eid,
                          float* __restrict__ s_norm) {
    int idx = blockIdx.x * 256 + threadIdx.x;
    const int total = NE + NN;
    if (idx >= total) return;
    int s, d, eid;
    if (idx < NE) { s = ei[idx]; d = ei[NE + idx]; eid = ea[idx]; }
    else          { s = d = idx - NE; eid = 0; }
    int pos = atomicAdd(&cursor[d], 1);
    s_src[pos] = s; s_eid[pos] = eid;
    s_norm[pos] = dinv[s] * dinv[d];
}

__global__ void k_h0(const int* __restrict__ x, const float* __restrict__ emb,
                     float* __restrict__ X, int n) {
    int v = blockIdx.x * 8 + (threadIdx.x >> 5);
    if (v >= n) return;
    int c4 = (threadIdx.x & 31) * 4;
    *(float4*)&X[v * DD + c4] = ld4(&emb[x[v] * DD + c4]);
}

// ---------------- per-layer kernels ----------------

// C[m][nn] = sum_k f(A[m][k]) * W[nn][k] + bias[nn],  f = optional BN(scale,shift)+ReLU
__global__ __launch_bounds__(256) void k_gemm(const float* __restrict__ A,
                                              const float* __restrict__ W,
                                              const float* __restrict__ bias,
                                              const float* __restrict__ scale,
                                              const float* __restrict__ shift,
                                              float* __restrict__ C,
                                              int n, int relu) {
    __shared__ float As[64][132];   // As[k][m] (transposed)
    __shared__ float Bs[64][132];   // Bs[k][nn] = W[nn][k]
    const int tid = threadIdx.x;
    const int tx = tid & 15;
    const int ty = tid >> 4;
    const int r0 = blockIdx.x * 128;
    float acc[8][8];
#pragma unroll
    for (int i = 0; i < 8; ++i)
#pragma unroll
        for (int j = 0; j < 8; ++j) acc[i][j] = 0.f;

    for (int k0 = 0; k0 < DD; k0 += 64) {
        float4 sc = ld4(&scale[k0 + tx * 4]);
        float4 sh = ld4(&shift[k0 + tx * 4]);
#pragma unroll
        for (int i = 0; i < 8; ++i) {
            int m = ty + 16 * i;
            int row = r0 + m;
            float4 v = make_float4(0.f, 0.f, 0.f, 0.f);
            if (row < n) v = ld4(&A[row * DD + k0 + tx * 4]);
            v.x = fmaf(v.x, sc.x, sh.x); v.y = fmaf(v.y, sc.y, sh.y);
            v.z = fmaf(v.z, sc.z, sh.z); v.w = fmaf(v.w, sc.w, sh.w);
            if (relu) {
                v.x = fmaxf(v.x, 0.f); v.y = fmaxf(v.y, 0.f);
                v.z = fmaxf(v.z, 0.f); v.w = fmaxf(v.w, 0.f);
            }
            As[tx * 4 + 0][m] = v.x; As[tx * 4 + 1][m] = v.y;
            As[tx * 4 + 2][m] = v.z; As[tx * 4 + 3][m] = v.w;
        }
#pragma unroll
        for (int i = 0; i < 8; ++i) {
            int nn = ty + 16 * i;
            float4 v = ld4(&W[nn * DD + k0 + tx * 4]);
            Bs[tx * 4 + 0][nn] = v.x; Bs[tx * 4 + 1][nn] = v.y;
            Bs[tx * 4 + 2][nn] = v.z; Bs[tx * 4 + 3][nn] = v.w;
        }
        __syncthreads();
#pragma unroll 4
        for (int k = 0; k < 64; ++k) {
            float4 a0 = *(float4*)&As[k][ty * 8];
            float4 a1 = *(float4*)&As[k][ty * 8 + 4];
            float4 b0 = *(float4*)&Bs[k][tx * 8];
            float4 b1 = *(float4*)&Bs[k][tx * 8 + 4];
            float a[8] = {a0.x, a0.y, a0.z, a0.w, a1.x, a1.y, a1.z, a1.w};
            float b[8] = {b0.x, b0.y, b0.z, b0.w, b1.x, b1.y, b1.z, b1.w};
#pragma unroll
            for (int i = 0; i < 8; ++i)
#pragma unroll
                for (int j = 0; j < 8; ++j) acc[i][j] = fmaf(a[i], b[j], acc[i][j]);
        }
        __syncthreads();
    }
    float4 bi0 = ld4(&bias[tx * 8]);
    float4 bi1 = ld4(&bias[tx * 8 + 4]);
#pragma unroll
    for (int i = 0; i < 8; ++i) {
        int row = r0 + ty * 8 + i;
        if (row < n) {
            float4 o0 = make_float4(acc[i][0] + bi0.x, acc[i][1] + bi0.y,
                                    acc[i][2] + bi0.z, acc[i][3] + bi0.w);
            float4 o1 = make_float4(acc[i][4] + bi1.x, acc[i][5] + bi1.y,
                                    acc[i][6] + bi1.z, acc[i][7] + bi1.w);
            *(float4*)&C[row * DD + tx * 8] = o0;
            *(float4*)&C[row * DD + tx * 8 + 4] = o1;
        }
    }
}

// agg[v][:] = sum over incoming edges p: norm[p] * (hl[src[p]][:] + etab[eid[p]][:])
__global__ __launch_bounds__(256) void k_agg(const float* __restrict__ hl,
                                             const float* __restrict__ etab,
                                             const int* __restrict__ row_ptr,
                                             const int* __restrict__ s_src,
                                             const int* __restrict__ s_eid,
                                             const float* __restrict__ s_norm,
                                             float* __restrict__ agg, int n) {
    int v = blockIdx.x * 8 + (threadIdx.x >> 5);
    if (v >= n) return;
    int c4 = (threadIdx.x & 31) * 4;
    int p0 = row_ptr[v], p1 = row_ptr[v + 1];
    float4 acc = make_float4(0.f, 0.f, 0.f, 0.f);
    for (int p = p0; p < p1; ++p) {
        int s = s_src[p];
        int e = s_eid[p];
        float nr = s_norm[p];
        float4 hv = ld4(&hl[s * DD + c4]);
        float4 ev = ld4(&etab[e * DD + c4]);
        acc.x = fmaf(nr, hv.x + ev.x, acc.x);
        acc.y = fmaf(nr, hv.y + ev.y, acc.y);
        acc.z = fmaf(nr, hv.z + ev.z, acc.z);
        acc.w = fmaf(nr, hv.w + ev.w, acc.w);
    }
    *(float4*)&agg[v * DD + c4] = acc;
}

__global__ __launch_bounds__(256) void k_bnstats(const float* __restrict__ X,
                                                 float* __restrict__ psumA,
                                                 float* __restrict__ psumB, int n) {
    __shared__ float ls[DD], lss[DD];
    int tid = threadIdx.x;
    if (tid < DD) { ls[tid] = 0.f; lss[tid] = 0.f; }
    __syncthreads();
    int half = tid >> 5;
    int c4 = (tid & 31) * 4;
    float4 s = make_float4(0.f, 0.f, 0.f, 0.f);
    float4 ss = make_float4(0.f, 0.f, 0.f, 0.f);
    for (int v = blockIdx.x * 8 + half; v < n; v += gridDim.x * 8) {
        float4 x = ld4(&X[v * DD + c4]);
        s.x += x.x; s.y += x.y; s.z += x.z; s.w += x.w;
        ss.x = fmaf(x.x, x.x, ss.x); ss.y = fmaf(x.y, x.y, ss.y);
        ss.z = fmaf(x.z, x.z, ss.z); ss.w = fmaf(x.w, x.w, ss.w);
    }
    atomicAdd(&ls[c4 + 0], s.x); atomicAdd(&ls[c4 + 1], s.y);
    atomicAdd(&ls[c4 + 2], s.z); atomicAdd(&ls[c4 + 3], s.w);
    atomicAdd(&lss[c4 + 0], ss.x); atomicAdd(&lss[c4 + 1], ss.y);
    atomicAdd(&lss[c4 + 2], ss.z); atomicAdd(&lss[c4 + 3], ss.w);
    __syncthreads();
    if (tid < DD) {
        psumA[blockIdx.x * DD + tid] = ls[tid];
        psumB[blockIdx.x * DD + tid] = lss[tid];
    }
}

__global__ void k_bnfinal(const float* __restrict__ psumA, const float* __restrict__ psumB,
                          const float* __restrict__ gamma, const float* __restrict__ beta,
                          float* __restrict__ scale, float* __restrict__ shift,
                          int n, int nblk) {
    int d = threadIdx.x;   // 128 threads
    float s = 0.f, ss = 0.f;
    for (int b = 0; b < nblk; ++b) { s += psumA[b * DD + d]; ss += psumB[b * DD + d]; }
    float mean = s / (float)n;
    float var = ss / (float)n - mean * mean;
    float sc = gamma[d] * rsqrtf(var + BN_EPS);
    scale[d] = sc;
    shift[d] = beta[d] - mean * sc;
}

__global__ void k_bnapply(float* __restrict__ X, const float* __restrict__ scale,
                          const float* __restrict__ shift, int total4) {
    int i = blockIdx.x * blockDim.x + threadIdx.x;
    int stride = gridDim.x * blockDim.x;
    for (; i < total4; i += stride) {
        int c = (i & 31) << 2;
        float4 v = *(float4*)&X[i * 4];
        float4 sc = ld4(&scale[c]);
        float4 sh = ld4(&shift[c]);
        v.x = fmaf(v.x, sc.x, sh.x); v.y = fmaf(v.y, sc.y, sh.y);
        v.z = fmaf(v.z, sc.z, sh.z); v.w = fmaf(v.w, sc.w, sh.w);
        *(float4*)&X[i * 4] = v;
    }
}

// ---------------- launch ----------------

extern "C" void kernel_launch(void* const* d_in, const int* in_sizes, int n_in,
                              void* d_out, int out_size, void* d_ws, size_t ws_size,
                              hipStream_t stream) {
    const int* x        = (const int*)d_in[0];
    const int* ei       = (const int*)d_in[1];
    const int* ea       = (const int*)d_in[2];
    const float* x_emb  = (const float*)d_in[3];
    const float* lin_w  = (const float*)d_in[4];
    const float* lin_b  = (const float*)d_in[5];
    const float* etab   = (const float*)d_in[6];
    const float* gamma  = (const float*)d_in[7];
    const float* beta   = (const float*)d_in[8];
    float* X = (float*)d_out;

    char* w = (char*)d_ws;
    size_t off = 0;
    auto alloc = [&](size_t bytes) -> void* {
        off = (off + 255) & ~(size_t)255;
        void* p = w + off;
        off += bytes;
        return p;
    };
    float* hl     = (float*)alloc((size_t)NN * DD * 4);
    int*   s_src  = (int*)alloc((size_t)(NE + NN) * 4);
    int*   s_eid  = (int*)alloc((size_t)(NE + NN) * 4);
    float* s_norm = (float*)alloc((size_t)(NE + NN) * 4);
    int*   deg_i  = (int*)alloc((size_t)NN * 4);
    int*   cnt    = (int*)alloc((size_t)NN * 4);
    int*   rowp   = (int*)alloc((size_t)(NN + 1) * 4);
    int*   cursor = (int*)alloc((size_t)NN * 4);
    float* dinv   = (float*)alloc((size_t)NN * 4);
    int*   bsum   = (int*)alloc((size_t)1024 * 4);
    int*   boffs  = (int*)alloc((size_t)1024 * 4);
    float* psumA  = (float*)alloc((size_t)256 * DD * 4);
    float* psumB  = (float*)alloc((size_t)256 * DD * 4);
    float* scale  = (float*)alloc((size_t)DD * 4);
    float* shift  = (float*)alloc((size_t)DD * 4);

    const int nblkS = (NN + 255) / 256;   // 391 <= 1024

    k_init<<<(NN + 255) / 256, 256, 0, stream>>>(deg_i, cnt, scale, shift, rowp, NN);
    k_count<<<(NE + 255) / 256, 256, 0, stream>>>(ei, deg_i, cnt);
    k_dinv<<<(NN + 255) / 256, 256, 0, stream>>>(deg_i, dinv, NN);
    k_scan_bsum<<<nblkS, 256, 0, stream>>>(cnt, bsum, NN);
    k_scan_boffs<<<1, 1024, 0, stream>>>(bsum, boffs, nblkS);
    k_scan_apply<<<nblkS, 256, 0, stream>>>(cnt, boffs, rowp, cursor, NN);
    k_scatter<<<(NE + NN + 255) / 256, 256, 0, stream>>>(ei, ea, dinv, cursor,
                                                         s_src, s_eid, s_norm);
    k_h0<<<(NN + 7) / 8, 256, 0, stream>>>(x, x_emb, X, NN);

    for (int l = 0; l < NL; ++l) {
        k_gemm<<<(NN + 127) / 128, 256, 0, stream>>>(X, lin_w + (size_t)l * DD * DD,
                                                     lin_b + (size_t)l * DD,
                                                     scale, shift, hl, NN, l > 0 ? 1 : 0);
        k_agg<<<(NN + 7) / 8, 256, 0, stream>>>(hl, etab + (size_t)l * NB * DD,
                                                rowp, s_src, s_eid, s_norm, X, NN);
        k_bnstats<<<256, 256, 0, stream>>>(X, psumA, psumB, NN);
        k_bnfinal<<<1, DD, 0, stream>>>(psumA, psumB, gamma + (size_t)l * DD,
                                        beta + (size_t)l * DD, scale, shift, NN, 256);
    }
    k_bnapply<<<(NN * DD / 4 + 255) / 256, 256, 0, stream>>>(X, scale, shift, NN * DD / 4);
}

// Round 3
// 1401.466 us; speedup vs baseline: 1.3076x; 1.1546x over previous
//
#include <hip/hip_runtime.h>

#define NN 100000
#define NE 1600000
#define DD 128
#define NL 5
#define NB 62
#define BN_EPS 1e-5f

typedef unsigned short ushort_t;
typedef unsigned int uint_t;

static __device__ __forceinline__ float4 ld4(const float* p) { return *(const float4*)p; }

static __device__ __forceinline__ float bfhi(uint_t u) {   // high bf16 of packed u32
    uint_t x = u & 0xFFFF0000u;
    return __builtin_bit_cast(float, x);
}
static __device__ __forceinline__ float bflo(uint_t u) {   // low bf16 of packed u32
    uint_t x = u << 16;
    return __builtin_bit_cast(float, x);
}
static __device__ __forceinline__ ushort_t f2bf(float f) { // RNE
    uint_t u = __builtin_bit_cast(uint_t, f);
    u += 0x7FFFu + ((u >> 16) & 1u);
    return (ushort_t)(u >> 16);
}

// ---------------- setup kernels ----------------

__global__ void k_init(int* deg_i, int* cnt, float* scale, float* shift,
                       int* row_ptr, int n) {
    int i = blockIdx.x * 256 + threadIdx.x;
    if (i < n) { deg_i[i] = 1; cnt[i] = 1; }   // self-loop contributes 1 to both
    if (i < DD) { scale[i] = 1.f; shift[i] = 0.f; }
    if (i == 0) row_ptr[NN] = NE + NN;         // total is static
}

__global__ void k_count(const int* __restrict__ ei, int* deg_i, int* cnt) {
    int e = blockIdx.x * 256 + threadIdx.x;
    if (e < NE) {
        atomicAdd(&deg_i[ei[e]], 1);        // src occurrences -> deg
        atomicAdd(&cnt[ei[NE + e]], 1);     // dst occurrences -> CSR row sizes
    }
}

__global__ void k_dinv(const int* __restrict__ deg_i, float* __restrict__ dinv, int n) {
    int i = blockIdx.x * 256 + threadIdx.x;
    if (i < n) dinv[i] = rsqrtf((float)deg_i[i]);
}

// convert edge_tab (L*NB*DD fp32) to bf16 once
__global__ void k_etabb(const float* __restrict__ etab, ushort_t* __restrict__ etabb,
                        int total) {
    int i = blockIdx.x * 256 + threadIdx.x;
    if (i < total) etabb[i] = f2bf(etab[i]);
}

// ---- 3-phase device-wide exclusive scan of cnt[0..NN) -> row_ptr, cursor ----

__global__ void k_scan_bsum(const int* __restrict__ cnt, int* __restrict__ bsum, int n) {
    __shared__ int s[256];
    int i = blockIdx.x * 256 + threadIdx.x;
    int v = (i < n) ? cnt[i] : 0;
    s[threadIdx.x] = v;
    __syncthreads();
    for (int off = 128; off > 0; off >>= 1) {
        if (threadIdx.x < off) s[threadIdx.x] += s[threadIdx.x + off];
        __syncthreads();
    }
    if (threadIdx.x == 0) bsum[blockIdx.x] = s[0];
}

__global__ void k_scan_boffs(const int* __restrict__ bsum, int* __restrict__ boffs,
                             int nblk) {
    __shared__ int s[1024];
    int t = threadIdx.x;
    int v = (t < nblk) ? bsum[t] : 0;
    s[t] = v;
    __syncthreads();
    for (int off = 1; off < 1024; off <<= 1) {
        int val = (t >= off) ? s[t - off] : 0;
        __syncthreads();
        s[t] += val;
        __syncthreads();
    }
    if (t < nblk) boffs[t] = s[t] - v;   // exclusive
}

__global__ void k_scan_apply(const int* __restrict__ cnt, const int* __restrict__ boffs,
                             int* __restrict__ row_ptr, int* __restrict__ cursor, int n) {
    __shared__ int s[256];
    int i = blockIdx.x * 256 + threadIdx.x;
    int t = threadIdx.x;
    int v = (i < n) ? cnt[i] : 0;
    s[t] = v;
    __syncthreads();
    for (int off = 1; off < 256; off <<= 1) {
        int val = (t >= off) ? s[t - off] : 0;
        __syncthreads();
        s[t] += val;
        __syncthreads();
    }
    if (i < n) {
        int excl = s[t] - v + boffs[blockIdx.x];
        row_ptr[i] = excl;
        cursor[i] = excl;
    }
}

// pack (src | eid<<20) into one stream
__global__ void k_scatter(const int* __restrict__ ei, const int* __restrict__ ea,
                          const float* __restrict__ dinv, int* cursor,
                          int* __restrict__ s_pack, float* __restrict__ s_norm) {
    int idx = blockIdx.x * 256 + threadIdx.x;
    const int total = NE + NN;
    if (idx >= total) return;
    int s, d, eid;
    if (idx < NE) { s = ei[idx]; d = ei[NE + idx]; eid = ea[idx]; }
    else          { s = d = idx - NE; eid = 0; }
    int pos = atomicAdd(&cursor[d], 1);
    s_pack[pos] = s | (eid << 20);
    s_norm[pos] = dinv[s] * dinv[d];
}

__global__ void k_h0(const int* __restrict__ x, const float* __restrict__ emb,
                     float* __restrict__ X, int n) {
    int v = blockIdx.x * 8 + (threadIdx.x >> 5);
    if (v >= n) return;
    int c4 = (threadIdx.x & 31) * 4;
    *(float4*)&X[v * DD + c4] = ld4(&emb[x[v] * DD + c4]);
}

// ---------------- per-layer kernels ----------------

// C[m][nn] = bf16( sum_k f(A[m][k]) * W[nn][k] + bias[nn] ), f = BN(scale,shift)+ReLU
__global__ __launch_bounds__(256) void k_gemm(const float* __restrict__ A,
                                              const float* __restrict__ W,
                                              const float* __restrict__ bias,
                                              const float* __restrict__ scale,
                                              const float* __restrict__ shift,
                                              ushort_t* __restrict__ C,
                                              int n, int relu) {
    __shared__ float As[64][132];   // As[k][m] (transposed)
    __shared__ float Bs[64][132];   // Bs[k][nn] = W[nn][k]
    const int tid = threadIdx.x;
    const int tx = tid & 15;
    const int ty = tid >> 4;
    const int r0 = blockIdx.x * 128;
    float acc[8][8];
#pragma unroll
    for (int i = 0; i < 8; ++i)
#pragma unroll
        for (int j = 0; j < 8; ++j) acc[i][j] = 0.f;

    for (int k0 = 0; k0 < DD; k0 += 64) {
        float4 sc = ld4(&scale[k0 + tx * 4]);
        float4 sh = ld4(&shift[k0 + tx * 4]);
#pragma unroll
        for (int i = 0; i < 8; ++i) {
            int m = ty + 16 * i;
            int row = r0 + m;
            float4 v = make_float4(0.f, 0.f, 0.f, 0.f);
            if (row < n) v = ld4(&A[row * DD + k0 + tx * 4]);
            v.x = fmaf(v.x, sc.x, sh.x); v.y = fmaf(v.y, sc.y, sh.y);
            v.z = fmaf(v.z, sc.z, sh.z); v.w = fmaf(v.w, sc.w, sh.w);
            if (relu) {
                v.x = fmaxf(v.x, 0.f); v.y = fmaxf(v.y, 0.f);
                v.z = fmaxf(v.z, 0.f); v.w = fmaxf(v.w, 0.f);
            }
            As[tx * 4 + 0][m] = v.x; As[tx * 4 + 1][m] = v.y;
            As[tx * 4 + 2][m] = v.z; As[tx * 4 + 3][m] = v.w;
        }
#pragma unroll
        for (int i = 0; i < 8; ++i) {
            int nn = ty + 16 * i;
            float4 v = ld4(&W[nn * DD + k0 + tx * 4]);
            Bs[tx * 4 + 0][nn] = v.x; Bs[tx * 4 + 1][nn] = v.y;
            Bs[tx * 4 + 2][nn] = v.z; Bs[tx * 4 + 3][nn] = v.w;
        }
        __syncthreads();
#pragma unroll 4
        for (int k = 0; k < 64; ++k) {
            float4 a0 = *(float4*)&As[k][ty * 8];
            float4 a1 = *(float4*)&As[k][ty * 8 + 4];
            float4 b0 = *(float4*)&Bs[k][tx * 8];
            float4 b1 = *(float4*)&Bs[k][tx * 8 + 4];
            float a[8] = {a0.x, a0.y, a0.z, a0.w, a1.x, a1.y, a1.z, a1.w};
            float b[8] = {b0.x, b0.y, b0.z, b0.w, b1.x, b1.y, b1.z, b1.w};
#pragma unroll
            for (int i = 0; i < 8; ++i)
#pragma unroll
                for (int j = 0; j < 8; ++j) acc[i][j] = fmaf(a[i], b[j], acc[i][j]);
        }
        __syncthreads();
    }
    float4 bi0 = ld4(&bias[tx * 8]);
    float4 bi1 = ld4(&bias[tx * 8 + 4]);
#pragma unroll
    for (int i = 0; i < 8; ++i) {
        int row = r0 + ty * 8 + i;
        if (row < n) {
            float o[8] = {acc[i][0] + bi0.x, acc[i][1] + bi0.y,
                          acc[i][2] + bi0.z, acc[i][3] + bi0.w,
                          acc[i][4] + bi1.x, acc[i][5] + bi1.y,
                          acc[i][6] + bi1.z, acc[i][7] + bi1.w};
            uint_t pk[4];
#pragma unroll
            for (int j = 0; j < 4; ++j)
                pk[j] = (uint_t)f2bf(o[2 * j]) | ((uint_t)f2bf(o[2 * j + 1]) << 16);
            *(uint4*)&C[row * DD + tx * 8] = make_uint4(pk[0], pk[1], pk[2], pk[3]);
        }
    }
}

// agg[v][:] = sum over incoming edges p: norm[p]*(bf16 hl[src[p]][:] + bf16 etab[eid[p]][:])
// 16 lanes per node, 8 bf16 (16B) per lane
__global__ __launch_bounds__(256) void k_agg(const ushort_t* __restrict__ hl,
                                             const ushort_t* __restrict__ etab,
                                             const int* __restrict__ row_ptr,
                                             const int* __restrict__ s_pack,
                                             const float* __restrict__ s_norm,
                                             float* __restrict__ agg, int n) {
    int v = blockIdx.x * 16 + (threadIdx.x >> 4);
    if (v >= n) return;
    int lane8 = (threadIdx.x & 15) * 8;
    int p0 = row_ptr[v], p1 = row_ptr[v + 1];
    float acc[8];
#pragma unroll
    for (int j = 0; j < 8; ++j) acc[j] = 0.f;
    for (int p = p0; p < p1; ++p) {
        int c = s_pack[p];
        float nr = s_norm[p];
        int s = c & 0xFFFFF;
        int e = c >> 20;
        uint4 hv = *(const uint4*)&hl[s * DD + lane8];
        uint4 ev = *(const uint4*)&etab[e * DD + lane8];
        acc[0] = fmaf(nr, bflo(hv.x) + bflo(ev.x), acc[0]);
        acc[1] = fmaf(nr, bfhi(hv.x) + bfhi(ev.x), acc[1]);
        acc[2] = fmaf(nr, bflo(hv.y) + bflo(ev.y), acc[2]);
        acc[3] = fmaf(nr, bfhi(hv.y) + bfhi(ev.y), acc[3]);
        acc[4] = fmaf(nr, bflo(hv.z) + bflo(ev.z), acc[4]);
        acc[5] = fmaf(nr, bfhi(hv.z) + bfhi(ev.z), acc[5]);
        acc[6] = fmaf(nr, bflo(hv.w) + bflo(ev.w), acc[6]);
        acc[7] = fmaf(nr, bfhi(hv.w) + bfhi(ev.w), acc[7]);
    }
    *(float4*)&agg[v * DD + lane8] = make_float4(acc[0], acc[1], acc[2], acc[3]);
    *(float4*)&agg[v * DD + lane8 + 4] = make_float4(acc[4], acc[5], acc[6], acc[7]);
}

__global__ __launch_bounds__(256) void k_bnstats(const float* __restrict__ X,
                                                 float* __restrict__ psumA,
                                                 float* __restrict__ psumB, int n) {
    __shared__ float ls[DD], lss[DD];
    int tid = threadIdx.x;
    if (tid < DD) { ls[tid] = 0.f; lss[tid] = 0.f; }
    __syncthreads();
    int half = tid >> 5;
    int c4 = (tid & 31) * 4;
    float4 s = make_float4(0.f, 0.f, 0.f, 0.f);
    float4 ss = make_float4(0.f, 0.f, 0.f, 0.f);
    for (int v = blockIdx.x * 8 + half; v < n; v += gridDim.x * 8) {
        float4 x = ld4(&X[v * DD + c4]);
        s.x += x.x; s.y += x.y; s.z += x.z; s.w += x.w;
        ss.x = fmaf(x.x, x.x, ss.x); ss.y = fmaf(x.y, x.y, ss.y);
        ss.z = fmaf(x.z, x.z, ss.z); ss.w = fmaf(x.w, x.w, ss.w);
    }
    atomicAdd(&ls[c4 + 0], s.x); atomicAdd(&ls[c4 + 1], s.y);
    atomicAdd(&ls[c4 + 2], s.z); atomicAdd(&ls[c4 + 3], s.w);
    atomicAdd(&lss[c4 + 0], ss.x); atomicAdd(&lss[c4 + 1], ss.y);
    atomicAdd(&lss[c4 + 2], ss.z); atomicAdd(&lss[c4 + 3], ss.w);
    __syncthreads();
    if (tid < DD) {
        psumA[blockIdx.x * DD + tid] = ls[tid];
        psumB[blockIdx.x * DD + tid] = lss[tid];
    }
}

__global__ void k_bnfinal(const float* __restrict__ psumA, const float* __restrict__ psumB,
                          const float* __restrict__ gamma, const float* __restrict__ beta,
                          float* __restrict__ scale, float* __restrict__ shift,
                          int n, int nblk) {
    int d = threadIdx.x;   // 128 threads
    float s = 0.f, ss = 0.f;
    for (int b = 0; b < nblk; ++b) { s += psumA[b * DD + d]; ss += psumB[b * DD + d]; }
    float mean = s / (float)n;
    float var = ss / (float)n - mean * mean;
    float sc = gamma[d] * rsqrtf(var + BN_EPS);
    scale[d] = sc;
    shift[d] = beta[d] - mean * sc;
}

__global__ void k_bnapply(float* __restrict__ X, const float* __restrict__ scale,
                          const float* __restrict__ shift, int total4) {
    int i = blockIdx.x * blockDim.x + threadIdx.x;
    int stride = gridDim.x * blockDim.x;
    for (; i < total4; i += stride) {
        int c = (i & 31) << 2;
        float4 v = *(float4*)&X[i * 4];
        float4 sc = ld4(&scale[c]);
        float4 sh = ld4(&shift[c]);
        v.x = fmaf(v.x, sc.x, sh.x); v.y = fmaf(v.y, sc.y, sh.y);
        v.z = fmaf(v.z, sc.z, sh.z); v.w = fmaf(v.w, sc.w, sh.w);
        *(float4*)&X[i * 4] = v;
    }
}

// ---------------- launch ----------------

extern "C" void kernel_launch(void* const* d_in, const int* in_sizes, int n_in,
                              void* d_out, int out_size, void* d_ws, size_t ws_size,
                              hipStream_t stream) {
    const int* x        = (const int*)d_in[0];
    const int* ei       = (const int*)d_in[1];
    const int* ea       = (const int*)d_in[2];
    const float* x_emb  = (const float*)d_in[3];
    const float* lin_w  = (const float*)d_in[4];
    const float* lin_b  = (const float*)d_in[5];
    const float* etab   = (const float*)d_in[6];
    const float* gamma  = (const float*)d_in[7];
    const float* beta   = (const float*)d_in[8];
    float* X = (float*)d_out;

    char* w = (char*)d_ws;
    size_t off = 0;
    auto alloc = [&](size_t bytes) -> void* {
        off = (off + 255) & ~(size_t)255;
        void* p = w + off;
        off += bytes;
        return p;
    };
    ushort_t* hl    = (ushort_t*)alloc((size_t)NN * DD * 2);
    ushort_t* etabb = (ushort_t*)alloc((size_t)NL * NB * DD * 2);
    int*   s_pack   = (int*)alloc((size_t)(NE + NN) * 4);
    float* s_norm   = (float*)alloc((size_t)(NE + NN) * 4);
    int*   deg_i    = (int*)alloc((size_t)NN * 4);
    int*   cnt      = (int*)alloc((size_t)NN * 4);
    int*   rowp     = (int*)alloc((size_t)(NN + 1) * 4);
    int*   cursor   = (int*)alloc((size_t)NN * 4);
    float* dinv     = (float*)alloc((size_t)NN * 4);
    int*   bsum     = (int*)alloc((size_t)1024 * 4);
    int*   boffs    = (int*)alloc((size_t)1024 * 4);
    float* psumA    = (float*)alloc((size_t)256 * DD * 4);
    float* psumB    = (float*)alloc((size_t)256 * DD * 4);
    float* scale    = (float*)alloc((size_t)DD * 4);
    float* shift    = (float*)alloc((size_t)DD * 4);

    const int nblkS = (NN + 255) / 256;   // 391 <= 1024
    const int etabTot = NL * NB * DD;

    k_init<<<(NN + 255) / 256, 256, 0, stream>>>(deg_i, cnt, scale, shift, rowp, NN);
    k_count<<<(NE + 255) / 256, 256, 0, stream>>>(ei, deg_i, cnt);
    k_dinv<<<(NN + 255) / 256, 256, 0, stream>>>(deg_i, dinv, NN);
    k_etabb<<<(etabTot + 255) / 256, 256, 0, stream>>>(etab, etabb, etabTot);
    k_scan_bsum<<<nblkS, 256, 0, stream>>>(cnt, bsum, NN);
    k_scan_boffs<<<1, 1024, 0, stream>>>(bsum, boffs, nblkS);
    k_scan_apply<<<nblkS, 256, 0, stream>>>(cnt, boffs, rowp, cursor, NN);
    k_scatter<<<(NE + NN + 255) / 256, 256, 0, stream>>>(ei, ea, dinv, cursor,
                                                         s_pack, s_norm);
    k_h0<<<(NN + 7) / 8, 256, 0, stream>>>(x, x_emb, X, NN);

    for (int l = 0; l < NL; ++l) {
        k_gemm<<<(NN + 127) / 128, 256, 0, stream>>>(X, lin_w + (size_t)l * DD * DD,
                                                     lin_b + (size_t)l * DD,
                                                     scale, shift, hl, NN, l > 0 ? 1 : 0);
        k_agg<<<(NN + 15) / 16, 256, 0, stream>>>(hl, etabb + (size_t)l * NB * DD,
                                                  rowp, s_pack, s_norm, X, NN);
        k_bnstats<<<256, 256, 0, stream>>>(X, psumA, psumB, NN);
        k_bnfinal<<<1, DD, 0, stream>>>(psumA, psumB, gamma + (size_t)l * DD,
                                        beta + (size_t)l * DD, scale, shift, NN, 256);
    }
    k_bnapply<<<(NN * DD / 4 + 255) / 256, 256, 0, stream>>>(X, scale, shift, NN * DD / 4);
}